// Round 3
// baseline (825.714 us; speedup 1.0000x reference)
//
#include <hip/hip_runtime.h>
#include <hip/hip_bf16.h>
#include <stdint.h>

#define E_EDGES 100000
#define IN_F    256
#define HID     128
#define KNB     16
#define NCHUNK  ((E_EDGES + 63) / 64)   // 1563
#define GEMM_GRID 512

// ---- sliced gather parameters ----
#define NS          8                    // T-row slices: 12500 rows = 3.2 MB, fits 4 MiB per-XCD L2
#define SLICE_ROWS  12500
#define GCHUNKS     8                    // 8 chunks x 16 edges = 128 edges/block
#define EDGES_PER_BLK (GCHUNKS * 16)
#define GATHER_GRID ((E_EDGES + EDGES_PER_BLK - 1) / EDGES_PER_BLK)   // 782

typedef short bf16x8 __attribute__((ext_vector_type(8)));
typedef float f32x4  __attribute__((ext_vector_type(4)));

__device__ __forceinline__ unsigned short f2bf(float f) {
    union { float f; unsigned u; } v; v.f = f;
    unsigned u = v.u;
    u += 0x7fffu + ((u >> 16) & 1u);   // round-to-nearest-even
    return (unsigned short)(u >> 16);
}

// W [256][128] fp32 -> Wtf: bf16 in MFMA B-fragment order. (unchanged)
__global__ void conv_w_kernel(const float* __restrict__ W, unsigned short* __restrict__ Wtf) {
    int d = blockIdx.x * 256 + threadIdx.x;   // 0..4095
    int f = d >> 6, L = d & 63;
    int k0 = f >> 3, ct = f & 7, quad = L >> 4, l15 = L & 15;
    int n  = ct * 16 + l15;
    int kb = (k0 * 4 + quad) * 8;
    const float* wp = W + (size_t)kb * HID + n;
    unsigned short h[8];
    #pragma unroll
    for (int j = 0; j < 8; ++j) h[j] = f2bf(wp[(size_t)j * HID]);
    uint4 o;
    o.x = (unsigned)h[0] | ((unsigned)h[1] << 16);
    o.y = (unsigned)h[2] | ((unsigned)h[3] << 16);
    o.z = (unsigned)h[4] | ((unsigned)h[5] << 16);
    o.w = (unsigned)h[6] | ((unsigned)h[7] << 16);
    *(uint4*)(Wtf + (size_t)d * 8) = o;
}

// T = A @ W + b (A fp32, converted in-reg), stored bf16 [E][128]. (unchanged)
__launch_bounds__(256, 2)
__global__ void gemm_t_kernel(const float* __restrict__ A,
                              const unsigned short* __restrict__ Wtf,
                              const float* __restrict__ bias,
                              unsigned short* __restrict__ T) {
    __shared__ unsigned short Bs[32768];   // 64 KB, fragment order
    const int tid  = threadIdx.x;
    const int wave = tid >> 6;
    const int lane = tid & 63;
    const int l15  = lane & 15;
    const int quad = lane >> 4;

    int c = blockIdx.x;
    int arow = c * 64 + wave * 16 + l15;
    if (arow >= E_EDGES) arow = E_EDGES - 1;
    const float* ap = A + (size_t)arow * IN_F + quad * 8;
    float4 af32[16];
    #pragma unroll
    for (int k0 = 0; k0 < 8; ++k0) {
        af32[2 * k0]     = *(const float4*)(ap + k0 * 32);
        af32[2 * k0 + 1] = *(const float4*)(ap + k0 * 32 + 4);
    }

    #pragma unroll
    for (int it = 0; it < 16; ++it) {
        int d = it * 256 + tid;
        *(uint4*)(Bs + (size_t)d * 8) = *(const uint4*)(Wtf + (size_t)d * 8);
    }

    float4 bv4[8];
    #pragma unroll
    for (int ct = 0; ct < 8; ++ct)
        bv4[ct] = *(const float4*)(bias + ct * 16 + quad * 4);

    __syncthreads();

    for (; c < NCHUNK; c += GEMM_GRID) {
        bf16x8 apre[8];
        #pragma unroll
        for (int k0 = 0; k0 < 8; ++k0) {
            float4 lo = af32[2 * k0], hi = af32[2 * k0 + 1];
            bf16x8 f;
            f[0] = (short)f2bf(lo.x); f[1] = (short)f2bf(lo.y);
            f[2] = (short)f2bf(lo.z); f[3] = (short)f2bf(lo.w);
            f[4] = (short)f2bf(hi.x); f[5] = (short)f2bf(hi.y);
            f[6] = (short)f2bf(hi.z); f[7] = (short)f2bf(hi.w);
            apre[k0] = f;
        }

        {
            int cn = c + GEMM_GRID;
            int arow2 = cn * 64 + wave * 16 + l15;
            if (arow2 >= E_EDGES) arow2 = E_EDGES - 1;
            const float* ap2 = A + (size_t)arow2 * IN_F + quad * 8;
            #pragma unroll
            for (int k0 = 0; k0 < 8; ++k0) {
                af32[2 * k0]     = *(const float4*)(ap2 + k0 * 32);
                af32[2 * k0 + 1] = *(const float4*)(ap2 + k0 * 32 + 4);
            }
        }
        __builtin_amdgcn_sched_barrier(0);

        f32x4 acc[8] = {};
        #pragma unroll
        for (int k0 = 0; k0 < 8; ++k0) {
            #pragma unroll
            for (int ct = 0; ct < 8; ++ct) {
                bf16x8 bf = *(const bf16x8*)(Bs + ((size_t)((k0 * 8 + ct) * 64 + lane)) * 8);
                acc[ct] = __builtin_amdgcn_mfma_f32_16x16x32_bf16(bf, apre[k0], acc[ct], 0, 0, 0);
            }
        }

        const int row = c * 64 + wave * 16 + l15;
        if (row < E_EDGES) {
            unsigned short* tp = T + (size_t)row * HID + quad * 4;
            #pragma unroll
            for (int ct = 0; ct < 8; ++ct) {
                unsigned short h0 = f2bf(acc[ct][0] + bv4[ct].x);
                unsigned short h1 = f2bf(acc[ct][1] + bv4[ct].y);
                unsigned short h2 = f2bf(acc[ct][2] + bv4[ct].z);
                unsigned short h3 = f2bf(acc[ct][3] + bv4[ct].w);
                uint2 o;
                o.x = (unsigned)h0 | ((unsigned)h1 << 16);
                o.y = (unsigned)h2 | ((unsigned)h3 << 16);
                *(uint2*)(tp + ct * 16) = o;
            }
        }
    }
}

__device__ __forceinline__ void acc_bf16x8(float a[8], uint4 v) {
    unsigned w[4] = { v.x, v.y, v.z, v.w };
    union { unsigned u; float f; } c;
    #pragma unroll
    for (int j = 0; j < 4; ++j) {
        c.u = w[j] << 16;          a[2 * j]     += c.f;
        c.u = w[j] & 0xffff0000u;  a[2 * j + 1] += c.f;
    }
}

// out[i] = t[i] + sum_k t[nbr[i][k]]
//
// Sliced gather, v2 (v2a: fix nontemporal-store type — clang ext_vector, not
// HIP float4). Round-1 failed on (a) rule-#20 scratch spill (VGPR=52 < 64
// accs => acc lived in scratch) and (b) MLP collapse (1-2 loads in flight).
// v2 keeps the slice sweep (NS=8 x 3.2 MB, fits per-XCD L2) but the inner
// loop is PREDICATED LOCKSTEP ROUNDS: each round advances all 8 chunks by <=1
// entry via three statically-unrolled passes:
//   (a) 8 unconditional LDS index reads (one lgkm wait),
//   (b) 8 exec-masked INDEPENDENT 16B global loads (no use in between -> all
//       8 in flight; masked-off lanes issue no memory requests),
//   (c) 8 exec-masked accumulates (whole-wave-false chunks skip via execz).
// All per-chunk state is indexed only in simple #pragma unroll loops ->
// guaranteed registers (VGPR_Count must read ~150+, NOT 52).
// Sort phase: per-edge counting sort by slice, nbr read straight from global
// (coalesced 64 B/thread); LDS strides 9/17 (coprime with 32 banks).
__launch_bounds__(256, 3)
__global__ void gather_sum_kernel(const unsigned short* __restrict__ T,
                                  const int* __restrict__ nbr,
                                  float* __restrict__ out) {
    __shared__ int ssort[EDGES_PER_BLK * 17];       // slice-sorted indices (8.5 KB)
    __shared__ int soff[EDGES_PER_BLK * 9];         // per-edge slice prefix, 9 ea (4.5 KB)
    __shared__ int scur[EDGES_PER_BLK * 9];         // scratch counters/cursors (4.5 KB)

    const int tid   = threadIdx.x;
    const int edge0 = blockIdx.x * EDGES_PER_BLK;
    const int el    = tid >> 4;        // 0..15
    const int lane  = tid & 15;        // feature group: feats lane*8..+8

    // ---- per-edge counting sort by slice (threads 0..127, one per edge) ----
    if (tid < EDGES_PER_BLK) {
        const int t = tid;
        int eg = edge0 + t;
        unsigned self = (unsigned)((eg < E_EDGES) ? eg : (E_EDGES - 1));
        const int* np = nbr + (size_t)((eg < E_EDGES) ? eg : (E_EDGES - 1)) * KNB;

        unsigned idxs[KNB];
        #pragma unroll
        for (int k = 0; k < KNB; k += 4) {
            uint4 q = *(const uint4*)(np + k);
            idxs[k] = q.x; idxs[k + 1] = q.y; idxs[k + 2] = q.z; idxs[k + 3] = q.w;
        }

        #pragma unroll
        for (int s = 0; s < NS; ++s) scur[t * 9 + s] = 0;
        #pragma unroll
        for (int k = 0; k < KNB; ++k)
            scur[t * 9 + idxs[k] / SLICE_ROWS] += 1;
        scur[t * 9 + self / SLICE_ROWS] += 1;

        int run = 0;
        #pragma unroll
        for (int s = 0; s < NS; ++s) {
            int c0 = scur[t * 9 + s];
            soff[t * 9 + s] = run;
            scur[t * 9 + s] = run;     // becomes scatter cursor
            run += c0;
        }
        soff[t * 9 + NS] = run;        // == 17

        #pragma unroll
        for (int k = 0; k < KNB; ++k) {
            int s = (int)(idxs[k] / SLICE_ROWS);
            ssort[t * 17 + scur[t * 9 + s]++] = (int)idxs[k];
        }
        {
            int s = (int)(self / SLICE_ROWS);
            ssort[t * 17 + scur[t * 9 + s]++] = (int)self;
        }
    }
    __syncthreads();

    const unsigned short* Tb = T + (size_t)lane * 8;

    // Per-chunk constant LDS bases (registers).
    int sbase[GCHUNKS], obase[GCHUNKS];
    #pragma unroll
    for (int c = 0; c < GCHUNKS; ++c) {
        sbase[c] = (c * 16 + el) * 17;
        obase[c] = (c * 16 + el) * 9;
    }

    float acc[GCHUNKS][8] = {};
    int   cur[GCHUNKS];
    #pragma unroll
    for (int c = 0; c < GCHUNKS; ++c) cur[c] = 0;

    for (int s = 0; s < NS; ++s) {
        int j[GCHUNKS], end[GCHUNKS];
        #pragma unroll
        for (int c = 0; c < GCHUNKS; ++c) {
            j[c]   = cur[c];
            end[c] = soff[obase[c] + s + 1];
            cur[c] = end[c];
        }

        while (true) {
            bool anyl = false;
            #pragma unroll
            for (int c = 0; c < GCHUNKS; ++c) anyl |= (j[c] < end[c]);
            if (!__any(anyl)) break;

            // (a) unconditional idx reads (clamped) — one lgkm drain total
            int idx[GCHUNKS];
            bool p[GCHUNKS];
            #pragma unroll
            for (int c = 0; c < GCHUNKS; ++c) {
                p[c] = j[c] < end[c];
                int jj = p[c] ? j[c] : 16;          // slot 16 always a valid index
                idx[c] = ssort[sbase[c] + jj];
            }
            // (b) exec-masked independent loads — all 8 in flight
            uint4 v[GCHUNKS];
            #pragma unroll
            for (int c = 0; c < GCHUNKS; ++c) {
                if (p[c]) v[c] = *(const uint4*)(Tb + (size_t)idx[c] * HID);
            }
            // (c) exec-masked accumulate + cursor advance
            #pragma unroll
            for (int c = 0; c < GCHUNKS; ++c) {
                if (p[c]) { acc_bf16x8(acc[c], v[c]); j[c] += 1; }
            }
        }
    }

    // Final store: nontemporal so the 50 MB out-stream doesn't evict slices.
    // NOTE: __builtin_nontemporal_store needs a clang ext_vector pointer
    // (f32x4), not HIP's float4 class.
    #pragma unroll
    for (int c = 0; c < GCHUNKS; ++c) {
        const int edge = edge0 + c * 16 + el;
        if (edge < E_EDGES) {
            float* op = out + (size_t)edge * HID + lane * 8;
            f32x4 o0 = { acc[c][0], acc[c][1], acc[c][2], acc[c][3] };
            f32x4 o1 = { acc[c][4], acc[c][5], acc[c][6], acc[c][7] };
            __builtin_nontemporal_store(o0, (f32x4*)op);
            __builtin_nontemporal_store(o1, (f32x4*)(op + 4));
        }
    }
}

extern "C" void kernel_launch(void* const* d_in, const int* in_sizes, int n_in,
                              void* d_out, int out_size, void* d_ws, size_t ws_size,
                              hipStream_t stream) {
    const float* edge_feats = (const float*)d_in[0];   // [E, 256] fp32
    const int*   neighbors  = (const int*)d_in[1];     // [E, 16] int32
    const float* W          = (const float*)d_in[2];   // [256, 128] fp32
    const float* b          = (const float*)d_in[3];   // [128] fp32
    float*       out        = (float*)d_out;           // [E, 128] fp32

    unsigned short* Wtf = (unsigned short*)d_ws;                      // 64 KB, fragment order
    unsigned short* T   = (unsigned short*)d_ws + (size_t)IN_F * HID; // 25.6 MB

    conv_w_kernel<<<16, 256, 0, stream>>>(W, Wtf);
    gemm_t_kernel<<<GEMM_GRID, 256, 0, stream>>>(edge_feats, Wtf, b, T);
    gather_sum_kernel<<<GATHER_GRID, 256, 0, stream>>>(T, neighbors, out);
}

// Round 4
// 247.994 us; speedup vs baseline: 3.3296x; 3.3296x over previous
//
#include <hip/hip_runtime.h>
#include <hip/hip_bf16.h>
#include <stdint.h>

#define E_EDGES 100000
#define IN_F    256
#define HID     128
#define KNB     16
#define NCHUNK  ((E_EDGES + 63) / 64)   // 1563
#define GEMM_GRID 512

// ---- sliced gather parameters ----
// NS=16 slices of 6250 rows = 1.6 MB bf16 each (margin vs 4 MiB per-XCD L2,
// tolerates cross-block drift). EPB=80 edges/block -> grid = 1250 exactly
// (100000 = 1250*80): no tail, no clamps. 5 blocks/CU co-resident under
// __launch_bounds__(256,5) => persistent grid, all blocks sweep slices
// together from t=0.
#define NS          16
#define SLICE_ROWS  6250
#define GCHUNKS     5                    // 5 chunks x 16 edges = 80 edges/block
#define EDGES_PER_BLK (GCHUNKS * 16)     // 80
#define GATHER_GRID (E_EDGES / EDGES_PER_BLK)   // 1250, exact

typedef short bf16x8 __attribute__((ext_vector_type(8)));
typedef float f32x4  __attribute__((ext_vector_type(4)));

__device__ __forceinline__ unsigned short f2bf(float f) {
    union { float f; unsigned u; } v; v.f = f;
    unsigned u = v.u;
    u += 0x7fffu + ((u >> 16) & 1u);   // round-to-nearest-even
    return (unsigned short)(u >> 16);
}

// W [256][128] fp32 -> Wtf: bf16 in MFMA B-fragment order. (unchanged)
__global__ void conv_w_kernel(const float* __restrict__ W, unsigned short* __restrict__ Wtf) {
    int d = blockIdx.x * 256 + threadIdx.x;   // 0..4095
    int f = d >> 6, L = d & 63;
    int k0 = f >> 3, ct = f & 7, quad = L >> 4, l15 = L & 15;
    int n  = ct * 16 + l15;
    int kb = (k0 * 4 + quad) * 8;
    const float* wp = W + (size_t)kb * HID + n;
    unsigned short h[8];
    #pragma unroll
    for (int j = 0; j < 8; ++j) h[j] = f2bf(wp[(size_t)j * HID]);
    uint4 o;
    o.x = (unsigned)h[0] | ((unsigned)h[1] << 16);
    o.y = (unsigned)h[2] | ((unsigned)h[3] << 16);
    o.z = (unsigned)h[4] | ((unsigned)h[5] << 16);
    o.w = (unsigned)h[6] | ((unsigned)h[7] << 16);
    *(uint4*)(Wtf + (size_t)d * 8) = o;
}

// T = A @ W + b (A fp32, converted in-reg), stored bf16 [E][128]. (unchanged)
__launch_bounds__(256, 2)
__global__ void gemm_t_kernel(const float* __restrict__ A,
                              const unsigned short* __restrict__ Wtf,
                              const float* __restrict__ bias,
                              unsigned short* __restrict__ T) {
    __shared__ unsigned short Bs[32768];   // 64 KB, fragment order
    const int tid  = threadIdx.x;
    const int wave = tid >> 6;
    const int lane = tid & 63;
    const int l15  = lane & 15;
    const int quad = lane >> 4;

    int c = blockIdx.x;
    int arow = c * 64 + wave * 16 + l15;
    if (arow >= E_EDGES) arow = E_EDGES - 1;
    const float* ap = A + (size_t)arow * IN_F + quad * 8;
    float4 af32[16];
    #pragma unroll
    for (int k0 = 0; k0 < 8; ++k0) {
        af32[2 * k0]     = *(const float4*)(ap + k0 * 32);
        af32[2 * k0 + 1] = *(const float4*)(ap + k0 * 32 + 4);
    }

    #pragma unroll
    for (int it = 0; it < 16; ++it) {
        int d = it * 256 + tid;
        *(uint4*)(Bs + (size_t)d * 8) = *(const uint4*)(Wtf + (size_t)d * 8);
    }

    float4 bv4[8];
    #pragma unroll
    for (int ct = 0; ct < 8; ++ct)
        bv4[ct] = *(const float4*)(bias + ct * 16 + quad * 4);

    __syncthreads();

    for (; c < NCHUNK; c += GEMM_GRID) {
        bf16x8 apre[8];
        #pragma unroll
        for (int k0 = 0; k0 < 8; ++k0) {
            float4 lo = af32[2 * k0], hi = af32[2 * k0 + 1];
            bf16x8 f;
            f[0] = (short)f2bf(lo.x); f[1] = (short)f2bf(lo.y);
            f[2] = (short)f2bf(lo.z); f[3] = (short)f2bf(lo.w);
            f[4] = (short)f2bf(hi.x); f[5] = (short)f2bf(hi.y);
            f[6] = (short)f2bf(hi.z); f[7] = (short)f2bf(hi.w);
            apre[k0] = f;
        }

        {
            int cn = c + GEMM_GRID;
            int arow2 = cn * 64 + wave * 16 + l15;
            if (arow2 >= E_EDGES) arow2 = E_EDGES - 1;
            const float* ap2 = A + (size_t)arow2 * IN_F + quad * 8;
            #pragma unroll
            for (int k0 = 0; k0 < 8; ++k0) {
                af32[2 * k0]     = *(const float4*)(ap2 + k0 * 32);
                af32[2 * k0 + 1] = *(const float4*)(ap2 + k0 * 32 + 4);
            }
        }
        __builtin_amdgcn_sched_barrier(0);

        f32x4 acc[8] = {};
        #pragma unroll
        for (int k0 = 0; k0 < 8; ++k0) {
            #pragma unroll
            for (int ct = 0; ct < 8; ++ct) {
                bf16x8 bf = *(const bf16x8*)(Bs + ((size_t)((k0 * 8 + ct) * 64 + lane)) * 8);
                acc[ct] = __builtin_amdgcn_mfma_f32_16x16x32_bf16(bf, apre[k0], acc[ct], 0, 0, 0);
            }
        }

        const int row = c * 64 + wave * 16 + l15;
        if (row < E_EDGES) {
            unsigned short* tp = T + (size_t)row * HID + quad * 4;
            #pragma unroll
            for (int ct = 0; ct < 8; ++ct) {
                unsigned short h0 = f2bf(acc[ct][0] + bv4[ct].x);
                unsigned short h1 = f2bf(acc[ct][1] + bv4[ct].y);
                unsigned short h2 = f2bf(acc[ct][2] + bv4[ct].z);
                unsigned short h3 = f2bf(acc[ct][3] + bv4[ct].w);
                uint2 o;
                o.x = (unsigned)h0 | ((unsigned)h1 << 16);
                o.y = (unsigned)h2 | ((unsigned)h3 << 16);
                *(uint2*)(tp + ct * 16) = o;
            }
        }
    }
}

// bf16x8 (as uint4) -> two f32x4, BY VALUE (no pointers => SROA-safe).
__device__ __forceinline__ float u2f(unsigned u) {
    union { unsigned u; float f; } c; c.u = u; return c.f;
}
__device__ __forceinline__ f32x4 declo(uint4 v) {
    f32x4 r = { u2f(v.x << 16), u2f(v.x & 0xffff0000u),
                u2f(v.y << 16), u2f(v.y & 0xffff0000u) };
    return r;
}
__device__ __forceinline__ f32x4 dechi(uint4 v) {
    f32x4 r = { u2f(v.z << 16), u2f(v.z & 0xffff0000u),
                u2f(v.w << 16), u2f(v.w & 0xffff0000u) };
    return r;
}

// out[i] = t[i] + sum_k t[nbr[i][k]]
//
// Sliced gather v3. v1/v2 both died of compiler scratch-spill (VGPR=52/84,
// WRITE_SIZE 1.3 GB of scratch traffic): array-typed per-chunk state +
// float[] pointer args defeated SROA (rule #20). v3 is spill-proof by
// construction: ALL per-chunk state is NAMED variables via macros, decode
// helpers return f32x4 by value, inner loop is the simple 2-deep pipelined
// run per (slice, chunk). Persistent grid (1250 blocks = 5/CU, launch_bounds
// (256,5) => VGPR cap ~102, named-state budget ~85) sweeps NS=16 slices of
// 1.6 MB in rough lockstep -> random T reads hit per-XCD L2.
// LDS strides are 17 (coprime with 32 banks).
// PASS SIGNATURE: WRITE_SIZE ~50 MB (no scratch), FETCH < 100 MB.
__launch_bounds__(256, 5)
__global__ void gather_sum_kernel(const unsigned short* __restrict__ T,
                                  const int* __restrict__ nbr,
                                  float* __restrict__ out) {
    __shared__ int ssort[EDGES_PER_BLK * 17];   // slice-sorted indices (5.4 KB)
    __shared__ int soff[EDGES_PER_BLK * 17];    // per-edge slice prefix, NS+1=17 (5.4 KB)
    __shared__ int scur[EDGES_PER_BLK * 17];    // counters/cursors, stride 17 (5.4 KB)

    const int tid   = threadIdx.x;
    const int edge0 = blockIdx.x * EDGES_PER_BLK;
    const int el    = tid >> 4;        // 0..15 edge-in-chunk
    const int lane  = tid & 15;        // feature group: feats lane*8..+8

    // ---- per-edge counting sort by slice (threads 0..79, one per edge) ----
    if (tid < EDGES_PER_BLK) {
        const int t = tid;
        const unsigned self = (unsigned)(edge0 + t);          // always < E_EDGES
        const int* np = nbr + (size_t)(edge0 + t) * KNB;

        unsigned idxs[KNB];
        #pragma unroll
        for (int k = 0; k < KNB; k += 4) {
            uint4 q = *(const uint4*)(np + k);
            idxs[k] = q.x; idxs[k + 1] = q.y; idxs[k + 2] = q.z; idxs[k + 3] = q.w;
        }

        #pragma unroll
        for (int s = 0; s < NS; ++s) scur[t * 17 + s] = 0;
        #pragma unroll
        for (int k = 0; k < KNB; ++k)
            scur[t * 17 + idxs[k] / SLICE_ROWS] += 1;
        scur[t * 17 + self / SLICE_ROWS] += 1;

        int run = 0;
        #pragma unroll
        for (int s = 0; s < NS; ++s) {
            int c0 = scur[t * 17 + s];
            soff[t * 17 + s] = run;
            scur[t * 17 + s] = run;     // becomes scatter cursor
            run += c0;
        }
        soff[t * 17 + NS] = run;        // == 17

        #pragma unroll
        for (int k = 0; k < KNB; ++k) {
            int s = (int)(idxs[k] / SLICE_ROWS);
            ssort[t * 17 + scur[t * 17 + s]++] = (int)idxs[k];
        }
        {
            int s = (int)(self / SLICE_ROWS);
            ssort[t * 17 + scur[t * 17 + s]++] = (int)self;
        }
    }
    __syncthreads();

    const unsigned short* Tb = T + (size_t)lane * 8;

    // ---- named per-chunk state (spill-proof: no arrays) ----
#define DECL_CHUNK(c) \
    f32x4 accL##c = {0.f, 0.f, 0.f, 0.f}; \
    f32x4 accH##c = {0.f, 0.f, 0.f, 0.f}; \
    int   cur##c  = 0; \
    const int base##c = (c * 16 + el) * 17;

    DECL_CHUNK(0) DECL_CHUNK(1) DECL_CHUNK(2) DECL_CHUNK(3) DECL_CHUNK(4)
#undef DECL_CHUNK

    // 2-deep pipelined run: iteration i issues idx/load for i+1 before
    // consuming i's value -> ds_read + vmem latencies overlap.
#define RUN_CHUNK(c) { \
    const int e_ = soff[base##c + s + 1]; \
    int j_ = cur##c; \
    cur##c = e_; \
    if (j_ < e_) { \
        int idx_ = ssort[base##c + j_]; \
        uint4 v_ = *(const uint4*)(Tb + (size_t)idx_ * HID); \
        for (++j_; j_ < e_; ++j_) { \
            int idx2_ = ssort[base##c + j_]; \
            uint4 v2_ = *(const uint4*)(Tb + (size_t)idx2_ * HID); \
            accL##c += declo(v_); \
            accH##c += dechi(v_); \
            v_ = v2_; \
        } \
        accL##c += declo(v_); \
        accH##c += dechi(v_); \
    } }

    for (int s = 0; s < NS; ++s) {
        RUN_CHUNK(0)
        RUN_CHUNK(1)
        RUN_CHUNK(2)
        RUN_CHUNK(3)
        RUN_CHUNK(4)
    }
#undef RUN_CHUNK

    // Final store: nontemporal f32x4 so the 50 MB out-stream doesn't evict
    // the L2 slice window.
#define STORE_CHUNK(c) { \
    const int edge_ = edge0 + c * 16 + el; \
    float* op_ = out + (size_t)edge_ * HID + lane * 8; \
    __builtin_nontemporal_store(accL##c, (f32x4*)op_); \
    __builtin_nontemporal_store(accH##c, (f32x4*)(op_ + 4)); \
    }

    STORE_CHUNK(0) STORE_CHUNK(1) STORE_CHUNK(2) STORE_CHUNK(3) STORE_CHUNK(4)
#undef STORE_CHUNK
}

extern "C" void kernel_launch(void* const* d_in, const int* in_sizes, int n_in,
                              void* d_out, int out_size, void* d_ws, size_t ws_size,
                              hipStream_t stream) {
    const float* edge_feats = (const float*)d_in[0];   // [E, 256] fp32
    const int*   neighbors  = (const int*)d_in[1];     // [E, 16] int32
    const float* W          = (const float*)d_in[2];   // [256, 128] fp32
    const float* b          = (const float*)d_in[3];   // [128] fp32
    float*       out        = (float*)d_out;           // [E, 128] fp32

    unsigned short* Wtf = (unsigned short*)d_ws;                      // 64 KB, fragment order
    unsigned short* T   = (unsigned short*)d_ws + (size_t)IN_F * HID; // 25.6 MB

    conv_w_kernel<<<16, 256, 0, stream>>>(W, Wtf);
    gemm_t_kernel<<<GEMM_GRID, 256, 0, stream>>>(edge_feats, Wtf, b, T);
    gather_sum_kernel<<<GATHER_GRID, 256, 0, stream>>>(T, neighbors, out);
}

// Round 6
// 243.728 us; speedup vs baseline: 3.3879x; 1.0175x over previous
//
#include <hip/hip_runtime.h>
#include <hip/hip_bf16.h>
#include <stdint.h>

#define E_EDGES 100000
#define IN_F    256
#define HID     128
#define KNB     16
#define NCHUNK  ((E_EDGES + 63) / 64)   // 1563
#define GEMM_GRID 512

// ---- sliced gather parameters ----
// NS=8 slices of 12500 rows = 3.2 MB bf16 each (fits 4 MiB per-XCD L2).
// EPB=80 -> grid = 1250 exactly (no tail). 4 blocks/CU co-resident under
// __launch_bounds__(256,4); persistent grid sweeps slices in rough lockstep.
#define NS          8
#define SLICE_ROWS  12500
#define GCHUNKS     5                    // 5 chunks x 16 edges = 80 edges/block
#define EDGES_PER_BLK (GCHUNKS * 16)     // 80
#define GATHER_GRID (E_EDGES / EDGES_PER_BLK)   // 1250, exact

typedef short bf16x8 __attribute__((ext_vector_type(8)));
typedef float f32x4  __attribute__((ext_vector_type(4)));

__device__ __forceinline__ unsigned short f2bf(float f) {
    union { float f; unsigned u; } v; v.f = f;
    unsigned u = v.u;
    u += 0x7fffu + ((u >> 16) & 1u);   // round-to-nearest-even
    return (unsigned short)(u >> 16);
}

// W [256][128] fp32 -> Wtf: bf16 in MFMA B-fragment order. (unchanged)
__global__ void conv_w_kernel(const float* __restrict__ W, unsigned short* __restrict__ Wtf) {
    int d = blockIdx.x * 256 + threadIdx.x;   // 0..4095
    int f = d >> 6, L = d & 63;
    int k0 = f >> 3, ct = f & 7, quad = L >> 4, l15 = L & 15;
    int n  = ct * 16 + l15;
    int kb = (k0 * 4 + quad) * 8;
    const float* wp = W + (size_t)kb * HID + n;
    unsigned short h[8];
    #pragma unroll
    for (int j = 0; j < 8; ++j) h[j] = f2bf(wp[(size_t)j * HID]);
    uint4 o;
    o.x = (unsigned)h[0] | ((unsigned)h[1] << 16);
    o.y = (unsigned)h[2] | ((unsigned)h[3] << 16);
    o.z = (unsigned)h[4] | ((unsigned)h[5] << 16);
    o.w = (unsigned)h[6] | ((unsigned)h[7] << 16);
    *(uint4*)(Wtf + (size_t)d * 8) = o;
}

// T = A @ W + b (A fp32, converted in-reg), stored bf16 [E][128]. (unchanged)
__launch_bounds__(256, 2)
__global__ void gemm_t_kernel(const float* __restrict__ A,
                              const unsigned short* __restrict__ Wtf,
                              const float* __restrict__ bias,
                              unsigned short* __restrict__ T) {
    __shared__ unsigned short Bs[32768];   // 64 KB, fragment order
    const int tid  = threadIdx.x;
    const int wave = tid >> 6;
    const int lane = tid & 63;
    const int l15  = lane & 15;
    const int quad = lane >> 4;

    int c = blockIdx.x;
    int arow = c * 64 + wave * 16 + l15;
    if (arow >= E_EDGES) arow = E_EDGES - 1;
    const float* ap = A + (size_t)arow * IN_F + quad * 8;
    float4 af32[16];
    #pragma unroll
    for (int k0 = 0; k0 < 8; ++k0) {
        af32[2 * k0]     = *(const float4*)(ap + k0 * 32);
        af32[2 * k0 + 1] = *(const float4*)(ap + k0 * 32 + 4);
    }

    #pragma unroll
    for (int it = 0; it < 16; ++it) {
        int d = it * 256 + tid;
        *(uint4*)(Bs + (size_t)d * 8) = *(const uint4*)(Wtf + (size_t)d * 8);
    }

    float4 bv4[8];
    #pragma unroll
    for (int ct = 0; ct < 8; ++ct)
        bv4[ct] = *(const float4*)(bias + ct * 16 + quad * 4);

    __syncthreads();

    for (; c < NCHUNK; c += GEMM_GRID) {
        bf16x8 apre[8];
        #pragma unroll
        for (int k0 = 0; k0 < 8; ++k0) {
            float4 lo = af32[2 * k0], hi = af32[2 * k0 + 1];
            bf16x8 f;
            f[0] = (short)f2bf(lo.x); f[1] = (short)f2bf(lo.y);
            f[2] = (short)f2bf(lo.z); f[3] = (short)f2bf(lo.w);
            f[4] = (short)f2bf(hi.x); f[5] = (short)f2bf(hi.y);
            f[6] = (short)f2bf(hi.z); f[7] = (short)f2bf(hi.w);
            apre[k0] = f;
        }

        {
            int cn = c + GEMM_GRID;
            int arow2 = cn * 64 + wave * 16 + l15;
            if (arow2 >= E_EDGES) arow2 = E_EDGES - 1;
            const float* ap2 = A + (size_t)arow2 * IN_F + quad * 8;
            #pragma unroll
            for (int k0 = 0; k0 < 8; ++k0) {
                af32[2 * k0]     = *(const float4*)(ap2 + k0 * 32);
                af32[2 * k0 + 1] = *(const float4*)(ap2 + k0 * 32 + 4);
            }
        }
        __builtin_amdgcn_sched_barrier(0);

        f32x4 acc[8] = {};
        #pragma unroll
        for (int k0 = 0; k0 < 8; ++k0) {
            #pragma unroll
            for (int ct = 0; ct < 8; ++ct) {
                bf16x8 bf = *(const bf16x8*)(Bs + ((size_t)((k0 * 8 + ct) * 64 + lane)) * 8);
                acc[ct] = __builtin_amdgcn_mfma_f32_16x16x32_bf16(bf, apre[k0], acc[ct], 0, 0, 0);
            }
        }

        const int row = c * 64 + wave * 16 + l15;
        if (row < E_EDGES) {
            unsigned short* tp = T + (size_t)row * HID + quad * 4;
            #pragma unroll
            for (int ct = 0; ct < 8; ++ct) {
                unsigned short h0 = f2bf(acc[ct][0] + bv4[ct].x);
                unsigned short h1 = f2bf(acc[ct][1] + bv4[ct].y);
                unsigned short h2 = f2bf(acc[ct][2] + bv4[ct].z);
                unsigned short h3 = f2bf(acc[ct][3] + bv4[ct].w);
                uint2 o;
                o.x = (unsigned)h0 | ((unsigned)h1 << 16);
                o.y = (unsigned)h2 | ((unsigned)h3 << 16);
                *(uint2*)(tp + ct * 16) = o;
            }
        }
    }
}

// bf16x8 (as uint4) -> two f32x4, BY VALUE (SROA-safe).
__device__ __forceinline__ float u2f(unsigned u) {
    union { unsigned u; float f; } c; c.u = u; return c.f;
}
__device__ __forceinline__ f32x4 declo(uint4 v) {
    f32x4 r = { u2f(v.x << 16), u2f(v.x & 0xffff0000u),
                u2f(v.y << 16), u2f(v.y & 0xffff0000u) };
    return r;
}
__device__ __forceinline__ f32x4 dechi(uint4 v) {
    f32x4 r = { u2f(v.z << 16), u2f(v.z & 0xffff0000u),
                u2f(v.w << 16), u2f(v.w & 0xffff0000u) };
    return r;
}

// out[i] = t[i] + sum_k t[nbr[i][k]]
//
// Sliced gather v4 = r4's spill-proof named-macro skeleton (WRITE_SIZE was
// clean 51 MB) + LOCKSTEP rounds for MLP (r4's serial per-chunk runs had
// MLP~1-2 -> 78 us despite halved fetch). Per while-iteration:
//   1. 5 LDS index reads (broadcast across the 16 lanes of an edge),
//      clamped to always-valid slot 16 when chunk done;
//   2. 5 UNCONDITIONAL global loads (no use before the sched_barrier ->
//      all 5 in flight; clamped loads waste a few % of L2-hit BW only);
//   3. branchless predicated accumulate (p ? v : 0; +0.0f is a no-op)
//      and j += p.
// NS=8 (3.2 MB slices, per-XCD-L2-resident; runs avg 2.1/chunk/slice ->
// ~24 lockstep iterations total vs r4's 80 serial mini-loops).
// PASS SIGNATURE: WRITE_SIZE ~51 MB (no spill), gather < 62 us (r0 flat).
__launch_bounds__(256, 4)
__global__ void gather_sum_kernel(const unsigned short* __restrict__ T,
                                  const int* __restrict__ nbr,
                                  float* __restrict__ out) {
    __shared__ int ssort[EDGES_PER_BLK * 17];   // slice-sorted indices (5.4 KB)
    __shared__ int soff[EDGES_PER_BLK * 9];     // per-edge slice prefix (2.9 KB)
    __shared__ int scur[EDGES_PER_BLK * 9];     // counters/cursors (2.9 KB)

    const int tid   = threadIdx.x;
    const int edge0 = blockIdx.x * EDGES_PER_BLK;
    const int el    = tid >> 4;        // 0..15 edge-in-chunk
    const int lane  = tid & 15;        // feature group: feats lane*8..+8

    // ---- per-edge counting sort by slice (threads 0..79, one per edge) ----
    if (tid < EDGES_PER_BLK) {
        const int t = tid;
        const unsigned self = (unsigned)(edge0 + t);          // always < E_EDGES
        const int* np = nbr + (size_t)(edge0 + t) * KNB;

        unsigned idxs[KNB];
        #pragma unroll
        for (int k = 0; k < KNB; k += 4) {
            uint4 q = *(const uint4*)(np + k);
            idxs[k] = q.x; idxs[k + 1] = q.y; idxs[k + 2] = q.z; idxs[k + 3] = q.w;
        }

        #pragma unroll
        for (int s = 0; s < NS; ++s) scur[t * 9 + s] = 0;
        #pragma unroll
        for (int k = 0; k < KNB; ++k)
            scur[t * 9 + idxs[k] / SLICE_ROWS] += 1;
        scur[t * 9 + self / SLICE_ROWS] += 1;

        int run = 0;
        #pragma unroll
        for (int s = 0; s < NS; ++s) {
            int c0 = scur[t * 9 + s];
            soff[t * 9 + s] = run;
            scur[t * 9 + s] = run;     // becomes scatter cursor
            run += c0;
        }
        soff[t * 9 + NS] = run;        // == 17

        #pragma unroll
        for (int k = 0; k < KNB; ++k) {
            int s = (int)(idxs[k] / SLICE_ROWS);
            ssort[t * 17 + scur[t * 9 + s]++] = (int)idxs[k];
        }
        {
            int s = (int)(self / SLICE_ROWS);
            ssort[t * 17 + scur[t * 9 + s]++] = (int)self;
        }
    }
    __syncthreads();

    const unsigned short* Tb = T + (size_t)lane * 8;

    // ---- named per-chunk state (spill-proof: no arrays) ----
#define DECL_CHUNK(c) \
    f32x4 accL##c = {0.f, 0.f, 0.f, 0.f}; \
    f32x4 accH##c = {0.f, 0.f, 0.f, 0.f}; \
    int   j##c = 0; \
    const int sb##c = (c * 16 + el) * 17; \
    const int ob##c = (c * 16 + el) * 9;

    DECL_CHUNK(0) DECL_CHUNK(1) DECL_CHUNK(2) DECL_CHUNK(3) DECL_CHUNK(4)
#undef DECL_CHUNK

    for (int s = 0; s < NS; ++s) {
        // Slice bounds for all 5 chunks (LDS, issued together).
        const int e0 = soff[ob0 + s + 1];
        const int e1 = soff[ob1 + s + 1];
        const int e2 = soff[ob2 + s + 1];
        const int e3 = soff[ob3 + s + 1];
        const int e4 = soff[ob4 + s + 1];

        while (true) {
            const bool p0 = j0 < e0, p1 = j1 < e1, p2 = j2 < e2,
                       p3 = j3 < e3, p4 = j4 < e4;
            if (!__any((int)(p0 | p1 | p2 | p3 | p4))) break;

            // 1. index reads (clamped to always-valid slot 16 when done)
            const int i0 = ssort[sb0 + (p0 ? j0 : 16)];
            const int i1 = ssort[sb1 + (p1 ? j1 : 16)];
            const int i2 = ssort[sb2 + (p2 ? j2 : 16)];
            const int i3 = ssort[sb3 + (p3 ? j3 : 16)];
            const int i4 = ssort[sb4 + (p4 ? j4 : 16)];

            // 2. unconditional loads — all 5 in flight before any use
            const uint4 v0 = *(const uint4*)(Tb + (size_t)i0 * HID);
            const uint4 v1 = *(const uint4*)(Tb + (size_t)i1 * HID);
            const uint4 v2 = *(const uint4*)(Tb + (size_t)i2 * HID);
            const uint4 v3 = *(const uint4*)(Tb + (size_t)i3 * HID);
            const uint4 v4 = *(const uint4*)(Tb + (size_t)i4 * HID);
            __builtin_amdgcn_sched_barrier(0);   // pin the load group above uses

            // 3. branchless predicated accumulate (+0.0 no-op when masked)
#define ACC_CHUNK(c) { \
            uint4 w_; \
            w_.x = p##c ? v##c.x : 0u; \
            w_.y = p##c ? v##c.y : 0u; \
            w_.z = p##c ? v##c.z : 0u; \
            w_.w = p##c ? v##c.w : 0u; \
            accL##c += declo(w_); \
            accH##c += dechi(w_); \
            j##c += (int)p##c; }

            ACC_CHUNK(0) ACC_CHUNK(1) ACC_CHUNK(2) ACC_CHUNK(3) ACC_CHUNK(4)
#undef ACC_CHUNK
        }
    }

    // Final store: nontemporal f32x4 so the 50 MB out-stream doesn't evict
    // the L2 slice window.
#define STORE_CHUNK(c) { \
    const int edge_ = edge0 + c * 16 + el; \
    float* op_ = out + (size_t)edge_ * HID + lane * 8; \
    __builtin_nontemporal_store(accL##c, (f32x4*)op_); \
    __builtin_nontemporal_store(accH##c, (f32x4*)(op_ + 4)); \
    }

    STORE_CHUNK(0) STORE_CHUNK(1) STORE_CHUNK(2) STORE_CHUNK(3) STORE_CHUNK(4)
#undef STORE_CHUNK
}

extern "C" void kernel_launch(void* const* d_in, const int* in_sizes, int n_in,
                              void* d_out, int out_size, void* d_ws, size_t ws_size,
                              hipStream_t stream) {
    const float* edge_feats = (const float*)d_in[0];   // [E, 256] fp32
    const int*   neighbors  = (const int*)d_in[1];     // [E, 16] int32
    const float* W          = (const float*)d_in[2];   // [256, 128] fp32
    const float* b          = (const float*)d_in[3];   // [128] fp32
    float*       out        = (float*)d_out;           // [E, 128] fp32

    unsigned short* Wtf = (unsigned short*)d_ws;                      // 64 KB, fragment order
    unsigned short* T   = (unsigned short*)d_ws + (size_t)IN_F * HID; // 25.6 MB

    conv_w_kernel<<<16, 256, 0, stream>>>(W, Wtf);
    gemm_t_kernel<<<GEMM_GRID, 256, 0, stream>>>(edge_feats, Wtf, b, T);
    gather_sum_kernel<<<GATHER_GRID, 256, 0, stream>>>(T, neighbors, out);
}